// Round 1
// baseline (252.943 us; speedup 1.0000x reference)
//
#include <hip/hip_runtime.h>

// Problem constants
#define B_N   2
#define H_LR  64
#define W_LR  64
#define HUP   128
#define WUP   128
#define GRP   4
#define NPT   9
#define EMB   32      // embedding dim per group (q/k)
#define CGRP  64      // x channels per group
#define KIN   256     // input channels for all convs
#define GE    128     // q/k channels
#define NOFF  288
#define NKOFF 416     // GE + NOFF

// ---------------------------------------------------------------------------
// Generic 1x1-conv GEMM: C[b, m, n] = bias[n] + sum_k W[n,k] * X[b, k, m]
// Output pixel-major. W/bias are a concat of (W1,b1) rows [0,N1) and (W2,b2)
// rows [N1,N). BM=64 (pixels), BN=64 (out ch), BK=32, 256 threads.
// ---------------------------------------------------------------------------
__global__ __launch_bounds__(256) void conv1x1_kernel(
    const float* __restrict__ X, const float* __restrict__ W1,
    const float* __restrict__ b1, const float* __restrict__ W2,
    const float* __restrict__ b2, float* __restrict__ C,
    int M, int N, int N1, int mtiles, int ntiles)
{
    __shared__ float sX[32][72];
    __shared__ float sW[32][72];
    int bx = blockIdx.x;
    int mt = bx % mtiles;
    int nt = (bx / mtiles) % ntiles;
    int b  = bx / (mtiles * ntiles);
    int m0 = mt * 64, n0 = nt * 64;
    int tid = threadIdx.x;
    int tx = tid & 15, ty = tid >> 4;

    float acc[4][4];
#pragma unroll
    for (int i = 0; i < 4; ++i)
#pragma unroll
        for (int j = 0; j < 4; ++j) acc[i][j] = 0.f;

    const float* Xb = X + (size_t)b * KIN * M;

    for (int k0 = 0; k0 < KIN; k0 += 32) {
#pragma unroll
        for (int r = 0; r < 8; ++r) {           // X tile: coalesced along m
            int idx = tid + r * 256;
            int kk = idx >> 6, mm = idx & 63;
            sX[kk][mm] = Xb[(size_t)(k0 + kk) * M + m0 + mm];
        }
#pragma unroll
        for (int r = 0; r < 8; ++r) {           // W tile: coalesced along k
            int idx = tid + r * 256;
            int kk = idx & 31, nn = idx >> 5;
            int n = n0 + nn;
            float v = 0.f;
            if (n < N)
                v = (n < N1) ? W1[(size_t)n * KIN + k0 + kk]
                             : W2[(size_t)(n - N1) * KIN + k0 + kk];
            sW[kk][nn] = v;
        }
        __syncthreads();
#pragma unroll
        for (int kk = 0; kk < 32; ++kk) {
            float xv[4], wv[4];
#pragma unroll
            for (int i = 0; i < 4; ++i) xv[i] = sX[kk][tx * 4 + i];
#pragma unroll
            for (int j = 0; j < 4; ++j) wv[j] = sW[kk][ty * 4 + j];
#pragma unroll
            for (int i = 0; i < 4; ++i)
#pragma unroll
                for (int j = 0; j < 4; ++j) acc[i][j] += xv[i] * wv[j];
        }
        __syncthreads();
    }

    int n = n0 + ty * 4;
    if (n < N) {
        float bb[4];
#pragma unroll
        for (int j = 0; j < 4; ++j) {
            int nn = n + j;
            bb[j] = (nn < N1) ? b1[nn] : b2[nn - N1];
        }
#pragma unroll
        for (int i = 0; i < 4; ++i) {
            int m = m0 + tx * 4 + i;
            float4 v;
            v.x = acc[i][0] + bb[0];
            v.y = acc[i][1] + bb[1];
            v.z = acc[i][2] + bb[2];
            v.w = acc[i][3] + bb[3];
            *(float4*)&C[((size_t)b * M + m) * N + n] = v;
        }
    }
}

// ---------------------------------------------------------------------------
// Transpose x [B, 256, 4096] -> xT [B, 4096, 256]  (pixel-major)
// ---------------------------------------------------------------------------
__global__ __launch_bounds__(256) void transpose_kernel(
    const float* __restrict__ X, float* __restrict__ XT)
{
    __shared__ float tile[32][33];
    int bx = blockIdx.x;
    int mt = bx % 128;
    int ct = (bx / 128) % 8;
    int b  = bx / 1024;
    int tid = threadIdx.x;
    int lx = tid & 31, lyb = tid >> 5;   // 8 rows per pass, 4 passes
#pragma unroll
    for (int r = 0; r < 4; ++r) {
        int c = ct * 32 + lyb + r * 8;
        int m = mt * 32 + lx;
        tile[lyb + r * 8][lx] = X[((size_t)b * 256 + c) * 4096 + m];
    }
    __syncthreads();
#pragma unroll
    for (int r = 0; r < 4; ++r) {
        int m = mt * 32 + lyb + r * 8;
        int c = ct * 32 + lx;
        XT[((size_t)b * 4096 + m) * 256 + c] = tile[lx][lyb + r * 8];
    }
}

// ---------------------------------------------------------------------------
// Fused deformable attention. One thread per (b, g, hup, wup).
// Block = 16x16 spatial tile. Grid = 8*8*4*2 = 512 blocks.
// ---------------------------------------------------------------------------
__global__ __launch_bounds__(256) void deform_kernel(
    const float* __restrict__ qws,   // [B, HUP*WUP, 128] pixel-major
    const float* __restrict__ koff,  // [B, 4096, 416]: n<128 = k, n>=128 = off
    const float* __restrict__ xT,    // [B, 4096, 256] pixel-major
    float* __restrict__ out)         // [B, 256, HUP, WUP]
{
    int bx = blockIdx.x;
    int tw = bx & 7, th = (bx >> 3) & 7, g = (bx >> 6) & 3, b = bx >> 8;
    int tid = threadIdx.x;
    int lx = tid & 15, ly = tid >> 4;
    int wup = tw * 16 + lx, hup = th * 16 + ly;
    int h = hup >> 1, w = wup >> 1;
    int ij = (hup & 1) * 2 + (wup & 1);
    int pix = h * W_LR + w;

    const float* kb = koff + ((size_t)b * 4096 + pix) * NKOFF;
    const float* qp = qws + ((size_t)b * (HUP * WUP) + hup * WUP + wup) * GE + g * EMB;

    float4 q[8];
#pragma unroll
    for (int r = 0; r < 8; ++r) q[r] = ((const float4*)qp)[r];

    float attn[NPT], pys[NPT], pxs[NPT];
    float by  = (hup + 0.5f) * 0.5f - 0.5f;
    float bxx = (wup + 0.5f) * 0.5f - 0.5f;

    // Pass 1: q . bilinear(k) per point
#pragma unroll
    for (int p = 0; p < NPT; ++p) {
        float offy = kb[GE + ((g * NPT + p) * 2 + 0) * 4 + ij];
        float offx = kb[GE + ((g * NPT + p) * 2 + 1) * 4 + ij];
        float py = offy + by, px = offx + bxx;
        pys[p] = py; pxs[p] = px;
        float y0f = floorf(py), x0f = floorf(px);
        float ty = py - y0f, tx = px - x0f;
        int y0 = (int)y0f, x0 = (int)x0f;
        float a = 0.f;
#pragma unroll
        for (int cy = 0; cy < 2; ++cy)
#pragma unroll
            for (int cx = 0; cx < 2; ++cx) {
                int yy = y0 + cy, xx = x0 + cx;
                if (yy >= 0 && yy < H_LR && xx >= 0 && xx < W_LR) {
                    float wv = (cy ? ty : 1.f - ty) * (cx ? tx : 1.f - tx);
                    const float4* kr = (const float4*)(
                        koff + ((size_t)b * 4096 + yy * W_LR + xx) * NKOFF + g * EMB);
                    float dot = 0.f;
#pragma unroll
                    for (int r = 0; r < 8; ++r) {
                        float4 kv = kr[r];
                        dot += q[r].x * kv.x + q[r].y * kv.y +
                               q[r].z * kv.z + q[r].w * kv.w;
                    }
                    a += wv * dot;
                }
            }
        attn[p] = a;
    }

    // Softmax over the 9 points
    float mx = attn[0];
#pragma unroll
    for (int p = 1; p < NPT; ++p) mx = fmaxf(mx, attn[p]);
    float s = 0.f;
#pragma unroll
    for (int p = 0; p < NPT; ++p) { attn[p] = __expf(attn[p] - mx); s += attn[p]; }
    float inv = 1.f / s;

    // Pass 2: weighted bilinear gather of x (64 channels)
    float4 acc[16];
#pragma unroll
    for (int r = 0; r < 16; ++r) acc[r] = make_float4(0.f, 0.f, 0.f, 0.f);

#pragma unroll
    for (int p = 0; p < NPT; ++p) {
        float py = pys[p], px = pxs[p];
        float y0f = floorf(py), x0f = floorf(px);
        float ty = py - y0f, tx = px - x0f;
        int y0 = (int)y0f, x0 = (int)x0f;
        float ap = attn[p] * inv;
#pragma unroll
        for (int cy = 0; cy < 2; ++cy)
#pragma unroll
            for (int cx = 0; cx < 2; ++cx) {
                int yy = y0 + cy, xx = x0 + cx;
                if (yy >= 0 && yy < H_LR && xx >= 0 && xx < W_LR) {
                    float wv = ap * (cy ? ty : 1.f - ty) * (cx ? tx : 1.f - tx);
                    const float4* xr = (const float4*)(
                        xT + ((size_t)b * 4096 + yy * W_LR + xx) * 256 + g * CGRP);
#pragma unroll
                    for (int r = 0; r < 16; ++r) {
                        float4 xv = xr[r];
                        acc[r].x += wv * xv.x; acc[r].y += wv * xv.y;
                        acc[r].z += wv * xv.z; acc[r].w += wv * xv.w;
                    }
                }
            }
    }

    float* ob = out + ((size_t)b * 256 + g * CGRP) * (HUP * WUP) + hup * WUP + wup;
#pragma unroll
    for (int r = 0; r < 16; ++r) {
        ob[(size_t)(r * 4 + 0) * (HUP * WUP)] = acc[r].x;
        ob[(size_t)(r * 4 + 1) * (HUP * WUP)] = acc[r].y;
        ob[(size_t)(r * 4 + 2) * (HUP * WUP)] = acc[r].z;
        ob[(size_t)(r * 4 + 3) * (HUP * WUP)] = acc[r].w;
    }
}

// ---------------------------------------------------------------------------
extern "C" void kernel_launch(void* const* d_in, const int* in_sizes, int n_in,
                              void* d_out, int out_size, void* d_ws, size_t ws_size,
                              hipStream_t stream)
{
    const float* y    = (const float*)d_in[0];
    const float* x    = (const float*)d_in[1];
    const float* Wq   = (const float*)d_in[2];
    const float* bq   = (const float*)d_in[3];
    const float* Wk   = (const float*)d_in[4];
    const float* bk   = (const float*)d_in[5];
    const float* Woff = (const float*)d_in[6];
    const float* boff = (const float*)d_in[7];
    float* out = (float*)d_out;

    float* qws    = (float*)d_ws;                             // 2*16384*128 = 4.19M floats
    float* koffws = qws + (size_t)B_N * HUP * WUP * GE;       // 2*4096*416  = 3.41M floats
    float* xTws   = koffws + (size_t)B_N * H_LR * W_LR * NKOFF; // 2*4096*256 = 2.10M floats

    // q = Wq @ y + bq, pixel-major [B, 16384, 128]
    conv1x1_kernel<<<dim3(B_N * 256 * 2), dim3(256), 0, stream>>>(
        y, Wq, bq, nullptr, nullptr, qws, HUP * WUP, GE, GE, 256, 2);

    // concat(k, off) = [Wk;Woff] @ x + [bk;boff], pixel-major [B, 4096, 416]
    conv1x1_kernel<<<dim3(B_N * 64 * 7), dim3(256), 0, stream>>>(
        x, Wk, bk, Woff, boff, koffws, H_LR * W_LR, NKOFF, GE, 64, 7);

    // xT [B, 4096, 256]
    transpose_kernel<<<dim3(2048), dim3(256), 0, stream>>>(x, xTws);

    // fused deformable attention
    deform_kernel<<<dim3(512), dim3(256), 0, stream>>>(qws, koffws, xTws, out);
}